// Round 3
// baseline (716.045 us; speedup 1.0000x reference)
//
#include <hip/hip_runtime.h>
#include <math.h>

#define SUB 5
#define TNO 201
#define HNO 64
#define TDATA 50000
#define ESYN 2000
#define ISYN 200
#define PAD (TNO/2)          // 100

// padded-C layout: per group of 4 columns we store 20 floats (+1 pad)
#define QE (ESYN/4)          // 500 float4-groups for E
#define QI (ISYN/4)          // 50 for I
#define CP 21                // stride 21 coprime with 32 -> conflict-free ds_read
#define LDSC ((QE+QI)*CP)    // 11550 floats = 46.2 KB -> 3 blocks/CU
#define NGRP (TDATA/4)       // 12500 groups of 4 rows

typedef float fx4 __attribute__((ext_vector_type(4)));

// ---------------------------------------------------------------------------
// Kernel 1: W_eff[s][c][k] = sum_h ff_w[s,h]*conv_w[s*64+h,c,k];  b_eff likewise
// ---------------------------------------------------------------------------
__global__ void weff_kernel(const float* __restrict__ conv_w,
                            const float* __restrict__ conv_b,
                            const float* __restrict__ ff_w,
                            const float* __restrict__ ff_b,
                            float* __restrict__ Weff,
                            float* __restrict__ beff) {
    int idx = blockIdx.x * blockDim.x + threadIdx.x;
    if (idx < SUB * 2 * TNO) {
        int s   = idx / (2 * TNO);
        int rem = idx - s * (2 * TNO);          // c*201 + k
        float acc = 0.f;
        #pragma unroll 8
        for (int h = 0; h < HNO; ++h)
            acc = fmaf(ff_w[s * HNO + h], conv_w[(size_t)(s * HNO + h) * (2 * TNO) + rem], acc);
        Weff[idx] = acc;
    }
    if (idx < SUB) {
        float acc = ff_b[idx];
        for (int h = 0; h < HNO; ++h)
            acc = fmaf(ff_w[idx * HNO + h], conv_b[idx * HNO + h], acc);
        beff[idx] = acc;
    }
}

// ---------------------------------------------------------------------------
// Kernel 2 (dominant, HBM-bound): grouping matmul, 4 rows/wave, software-
// pipelined nontemporal loads (prefetch it+1 while FMA-ing it; last iteration
// prefetches the NEXT group's first tile so the reduction overlaps HBM
// latency; I-loads issued at group start, consumed at group end).
// ---------------------------------------------------------------------------
__device__ inline float foldp(float a, float b, int m, int lane) {
    float send = (lane & m) ? a : b;
    float recv = __shfl_xor(send, m);
    return ((lane & m) ? b : a) + recv;
}

template<int CH0>
__device__ inline void fma_block(float (&acc)[4][10],
                                 fx4 v0, fx4 v1, fx4 v2, fx4 v3,
                                 const float* c) {
    #pragma unroll
    for (int e = 0; e < 4; ++e) {
        #pragma unroll
        for (int s = 0; s < 5; ++s) {
            float w = c[e * 5 + s];
            acc[0][2 * s + CH0] = fmaf(v0[e], w, acc[0][2 * s + CH0]);
            acc[1][2 * s + CH0] = fmaf(v1[e], w, acc[1][2 * s + CH0]);
            acc[2][2 * s + CH0] = fmaf(v2[e], w, acc[2][2 * s + CH0]);
            acc[3][2 * s + CH0] = fmaf(v3[e], w, acc[3][2 * s + CH0]);
        }
    }
}

__global__ __launch_bounds__(256, 3) void group_kernel(
        const float* __restrict__ Se, const float* __restrict__ Si,
        const float* __restrict__ rawE, const float* __restrict__ rawI,
        const float* __restrict__ temp,
        float* __restrict__ Sg) {
    __shared__ float ldsC[LDSC];

    // ---- fused softmax over subunit axis, padded layout ----
    float invT = 1.0f / temp[0];
    for (int j = threadIdx.x; j < ESYN + ISYN; j += blockDim.x) {
        float v[SUB];
        float* dst;
        if (j < ESYN) {
            #pragma unroll
            for (int s = 0; s < SUB; ++s) v[s] = rawE[s * ESYN + j] * invT;
            dst = ldsC + (j >> 2) * CP + (j & 3) * SUB;
        } else {
            int jj = j - ESYN;
            #pragma unroll
            for (int s = 0; s < SUB; ++s) v[s] = rawI[s * ISYN + jj] * invT;
            dst = ldsC + QE * CP + (jj >> 2) * CP + (jj & 3) * SUB;
        }
        float m = fmaxf(fmaxf(fmaxf(v[0], v[1]), fmaxf(v[2], v[3])), v[4]);
        float sum = 0.f;
        #pragma unroll
        for (int s = 0; s < SUB; ++s) { v[s] = expf(v[s] - m); sum += v[s]; }
        float r = 1.0f / sum;
        #pragma unroll
        for (int s = 0; s < SUB; ++s) dst[s] = v[s] * r;
    }
    __syncthreads();

    const float* lE = ldsC;
    const float* lI = ldsC + QE * CP;
    int wave = threadIdx.x >> 6;
    int lane = threadIdx.x & 63;
    int nw   = (gridDim.x * blockDim.x) >> 6;          // 3072 waves
    int wid  = blockIdx.x * (blockDim.x >> 6) + wave;  // < 3072 < NGRP always

    const fx4* SeV = (const fx4*)Se;
    const fx4* SiV = (const fx4*)Si;

    // initial prefetch: group wid, it=0, q=lane
    fx4 c0, c1, c2, c3;
    {
        size_t b = (size_t)wid * 4 * QE;
        c0 = __builtin_nontemporal_load(SeV + b + 0 * QE + lane);
        c1 = __builtin_nontemporal_load(SeV + b + 1 * QE + lane);
        c2 = __builtin_nontemporal_load(SeV + b + 2 * QE + lane);
        c3 = __builtin_nontemporal_load(SeV + b + 3 * QE + lane);
    }

    for (int g = wid; g < NGRP; g += nw) {
        size_t bE = (size_t)g * 4 * QE;

        // issue I loads now; consumed after the E loop
        fx4 i0, i1, i2, i3;
        {
            int li = (lane < QI) ? lane : 0;
            size_t bI = (size_t)g * 4 * QI;
            i0 = __builtin_nontemporal_load(SiV + bI + 0 * QI + li);
            i1 = __builtin_nontemporal_load(SiV + bI + 1 * QI + li);
            i2 = __builtin_nontemporal_load(SiV + bI + 2 * QI + li);
            i3 = __builtin_nontemporal_load(SiV + bI + 3 * QI + li);
        }

        float acc[4][10];
        #pragma unroll
        for (int r = 0; r < 4; ++r)
            #pragma unroll
            for (int c = 0; c < 10; ++c) acc[r][c] = 0.f;

        int gn = g + nw;
        size_t bN = (size_t)((gn < NGRP) ? gn : wid) * 4 * QE;  // clamped: values unused if invalid

        #pragma unroll
        for (int it = 0; it < 8; ++it) {
            // prefetch: it<7 -> same group next tile; it==7 -> next group tile 0
            fx4 n0, n1, n2, n3;
            if (it < 7) {
                int qn = lane + ((it + 1) << 6);
                int qc = (qn < QE) ? qn : 0;       // only it==6 needs the clamp
                n0 = __builtin_nontemporal_load(SeV + bE + 0 * QE + qc);
                n1 = __builtin_nontemporal_load(SeV + bE + 1 * QE + qc);
                n2 = __builtin_nontemporal_load(SeV + bE + 2 * QE + qc);
                n3 = __builtin_nontemporal_load(SeV + bE + 3 * QE + qc);
            } else {
                n0 = __builtin_nontemporal_load(SeV + bN + 0 * QE + lane);
                n1 = __builtin_nontemporal_load(SeV + bN + 1 * QE + lane);
                n2 = __builtin_nontemporal_load(SeV + bN + 2 * QE + lane);
                n3 = __builtin_nontemporal_load(SeV + bN + 3 * QE + lane);
            }
            // consume current tile
            int q = lane + (it << 6);
            if (it == 7) {
                bool ok = (q < QE);                // lanes >= 52 are past row end
                fx4 z = (fx4)0.f;
                if (!ok) { c0 = z; c1 = z; c2 = z; c3 = z; }
                int qc = ok ? q : 0;
                fma_block<0>(acc, c0, c1, c2, c3, lE + qc * CP);
            } else {
                fma_block<0>(acc, c0, c1, c2, c3, lE + q * CP);
            }
            c0 = n0; c1 = n1; c2 = n2; c3 = n3;
        }

        // I contribution (lanes 0..49)
        if (lane < QI) fma_block<1>(acc, i0, i1, i2, i3, lI + lane * CP);

        // ---- fold-tree reduction: 40 accs -> 5 regs, then 3-step butterfly ----
        float f1[20], f2[10], f3[5];
        {
            const float* a = &acc[0][0];
            #pragma unroll
            for (int j = 0; j < 20; ++j) f1[j] = foldp(a[2 * j], a[2 * j + 1], 1, lane);
            #pragma unroll
            for (int j = 0; j < 10; ++j) f2[j] = foldp(f1[2 * j], f1[2 * j + 1], 2, lane);
            #pragma unroll
            for (int j = 0; j < 5; ++j)  f3[j] = foldp(f2[2 * j], f2[2 * j + 1], 4, lane);
            #pragma unroll
            for (int j = 0; j < 5; ++j) {
                f3[j] += __shfl_xor(f3[j], 8);
                f3[j] += __shfl_xor(f3[j], 16);
                f3[j] += __shfl_xor(f3[j], 32);
            }
        }
        if (lane < 8) {
            #pragma unroll
            for (int j = 0; j < 5; ++j) {
                int i = 8 * j + lane;              // i in [0,40)
                int r = i / 10, c = i - 10 * r;
                Sg[(size_t)(g * 4 + r) * 10 + c] = f3[j];
            }
        }
    }
}

// ---------------------------------------------------------------------------
// Kernel 3: effective 10-ch 201-tap conv + LeakyReLU + root + LeakyReLU + V_o.
// Sg staged as 5 per-subunit planes of (E,I) float2 pairs -> linear 8B/lane
// ds_read_b64, conflict-free. Weff read with wave-uniform indices (s_load).
// ---------------------------------------------------------------------------
#define OB 128
#define ORS (OB + TNO - 1)     // 328 staged rows
#define PPITCH (ORS * 2 + 2)   // 658 floats per plane (8B-aligned pitch)

__global__ __launch_bounds__(128) void out_kernel(
        const float* __restrict__ Sg, const float* __restrict__ Weff,
        const float* __restrict__ beff, const float* __restrict__ root_w,
        const float* __restrict__ root_b, const float* __restrict__ V_o,
        float* __restrict__ out) {
    __shared__ float sP[SUB * PPITCH];   // 13.2 KB

    int tid = threadIdx.x;
    int t0  = blockIdx.x * OB;

    for (int i = tid; i < ORS * SUB; i += OB) {
        int rr = i % ORS, s = i / ORS;
        int rg = t0 - PAD + rr;
        float2 val = make_float2(0.f, 0.f);
        if (rg >= 0 && rg < TDATA) val = *(const float2*)(Sg + (size_t)rg * 10 + s * 2);
        *(float2*)(sP + s * PPITCH + rr * 2) = val;
    }
    __syncthreads();

    int t = t0 + tid;
    if (t >= TDATA) return;

    float acc[SUB];
    #pragma unroll
    for (int s = 0; s < SUB; ++s) acc[s] = beff[s];

    #pragma unroll 3
    for (int k = 0; k < TNO; ++k) {
        int r2 = (tid + k) * 2;
        #pragma unroll
        for (int s = 0; s < SUB; ++s) {
            float2 ei = *(const float2*)(sP + s * PPITCH + r2);
            acc[s] = fmaf(ei.x, Weff[s * 402 + k],
                     fmaf(ei.y, Weff[s * 402 + 201 + k], acc[s]));
        }
    }
    auto lk = [](float x) { return x > 0.f ? x : 0.01f * x; };
    float root = root_b[0];
    #pragma unroll
    for (int s = 0; s < SUB; ++s) root += lk(acc[s]) * root_w[s];
    out[t] = lk(root) + V_o[0];
}

// ---------------------------------------------------------------------------
extern "C" void kernel_launch(void* const* d_in, const int* in_sizes, int n_in,
                              void* d_out, int out_size, void* d_ws, size_t ws_size,
                              hipStream_t stream) {
    (void)in_sizes; (void)n_in; (void)out_size; (void)ws_size;
    const float* Se     = (const float*)d_in[0];
    const float* Si     = (const float*)d_in[1];
    const float* temp   = (const float*)d_in[2];
    const float* rawE   = (const float*)d_in[3];
    const float* rawI   = (const float*)d_in[4];
    const float* conv_w = (const float*)d_in[5];
    const float* conv_b = (const float*)d_in[6];
    const float* ff_w   = (const float*)d_in[7];
    const float* ff_b   = (const float*)d_in[8];
    const float* root_w = (const float*)d_in[9];
    const float* root_b = (const float*)d_in[10];
    const float* V_o    = (const float*)d_in[11];
    float* out = (float*)d_out;

    float* ws   = (float*)d_ws;
    float* Weff = ws;            // 2010 floats
    float* beff = ws + 2016;     // 5
    float* Sg   = ws + 2048;     // 500000 floats (T x 10 interleaved)

    hipLaunchKernelGGL(weff_kernel, dim3(8), dim3(256), 0, stream,
                       conv_w, conv_b, ff_w, ff_b, Weff, beff);
    // 768 blocks = 3/CU (46.2 KB LDS), 3072 waves, 4 rows per wave per step
    hipLaunchKernelGGL(group_kernel, dim3(768), dim3(256), 0, stream,
                       Se, Si, rawE, rawI, temp, Sg);
    hipLaunchKernelGGL(out_kernel, dim3((TDATA + OB - 1) / OB), dim3(128), 0, stream,
                       Sg, Weff, beff, root_w, root_b, V_o, out);
}